// Round 1
// baseline (1109.909 us; speedup 1.0000x reference)
//
#include <hip/hip_runtime.h>

#define D 128
#define NPB 32  // nodes per MLP block

typedef __attribute__((ext_vector_type(8))) short short8;
typedef __attribute__((ext_vector_type(4))) float f32x4;

__device__ inline unsigned short f2bf(float f) {
    unsigned int u = __float_as_uint(f);
    u += 0x7fffu + ((u >> 16) & 1u);   // round-to-nearest-even
    return (unsigned short)(u >> 16);
}

// ---- pack W1 [2D,D] and W2 [D,D] into MFMA B-fragment order (bf16) + zero counts ----
// B-frag for (col-tile c, k-step s): lane l holds B[k][n], n = c*16 + (l&15),
// k = s*32 + (l>>4)*8 + j, j=0..7 contiguous -> one 16B load per fragment.
__global__ __launch_bounds__(256) void setup_kernel(
    const float* __restrict__ W1, const float* __restrict__ W2,
    unsigned short* __restrict__ pW1, unsigned short* __restrict__ pW2,
    int* __restrict__ counts, int n_nodes)
{
    int idx = blockIdx.x * 256 + threadIdx.x;
    if (idx < 32768) {            // 8 c-tiles * 8 s-steps * 64 lanes * 8
        int j = idx & 7, lane = (idx >> 3) & 63, s = (idx >> 9) & 7, c = idx >> 12;
        int k = s * 32 + ((lane >> 4) << 3) + j;
        int n = (c << 4) + (lane & 15);
        pW1[idx] = f2bf(W1[k * D + n]);
    } else if (idx < 49152) {     // 8 c-tiles * 4 s-steps * 64 lanes * 8
        int i2 = idx - 32768;
        int j = i2 & 7, lane = (i2 >> 3) & 63, s = (i2 >> 9) & 3, c = i2 >> 11;
        int k = s * 32 + ((lane >> 4) << 3) + j;
        int n = (c << 4) + (lane & 15);
        pW2[i2] = f2bf(W2[k * D + n]);
    }
    // zero histogram counts (replaces the separate hipMemsetAsync dispatch)
    for (int i = idx; i < n_nodes; i += gridDim.x * 256) counts[i] = 0;
}

// ---- CSR build: histogram -> (reduce, fused scan) -> reorder ----
__global__ __launch_bounds__(256) void hist_kernel(
    const int* __restrict__ recv, int* __restrict__ counts, int n_edges)
{
    int e = blockIdx.x * 256 + threadIdx.x;
    if (e < n_edges) atomicAdd(&counts[recv[e]], 1);
}

__global__ __launch_bounds__(256) void reduce_kernel(
    const int* __restrict__ counts, int* __restrict__ blocksum, int n)
{
    __shared__ int s[256];
    int t = threadIdx.x, i = blockIdx.x * 256 + t;
    s[t] = (i < n) ? counts[i] : 0;
    __syncthreads();
    for (int off = 128; off > 0; off >>= 1) {
        if (t < off) s[t] += s[t + off];
        __syncthreads();
    }
    if (t == 0) blocksum[blockIdx.x] = s[0];
}

// fused: block b computes its own exclusive offset by summing blocksum[0..b)
// (782 ints, L2-resident -> trivial), then does the intra-block scan.
__global__ __launch_bounds__(256) void scan_kernel(
    const int* __restrict__ counts, const int* __restrict__ blocksum,
    int* __restrict__ starts, int* __restrict__ cursor, int n)
{
    __shared__ int s[256];
    int t = threadIdx.x, b = blockIdx.x, i = b * 256 + t;

    // block offset = sum of preceding block sums
    int acc = 0;
    for (int j = t; j < b; j += 256) acc += blocksum[j];
    s[t] = acc;
    __syncthreads();
    for (int off = 128; off > 0; off >>= 1) {
        if (t < off) s[t] += s[t + off];
        __syncthreads();
    }
    int blockoff = s[0];
    __syncthreads();   // everyone has read s[0] before s[] is reused

    // intra-block inclusive scan
    int v = (i < n) ? counts[i] : 0;
    s[t] = v;
    __syncthreads();
    for (int off = 1; off < 256; off <<= 1) {
        int add = (t >= off) ? s[t - off] : 0;
        __syncthreads();
        s[t] += add;
        __syncthreads();
    }
    int excl = s[t] - v + blockoff;
    if (i < n) {
        starts[i] = excl;
        cursor[i] = excl;
        if (i == n - 1) starts[n] = excl + v;
    }
}

__global__ __launch_bounds__(256) void reorder_kernel(
    const int* __restrict__ recv, int* __restrict__ cursor,
    int* __restrict__ edge_ids, int* __restrict__ recvs, int n_edges)
{
    int e = blockIdx.x * 256 + threadIdx.x;
    if (e < n_edges) {
        int r = recv[e];
        int pos = atomicAdd(&cursor[r], 1);
        edge_ids[pos] = e;
        recvs[pos] = r;       // receiver per sorted slot (for edge-parallel gather)
    }
}

// ---- fused gather + MLP (bf16 MFMA, fp32 accumulate) ----
// Gather is EDGE-PARALLEL: the block's 32 nodes own one contiguous CSR slot
// range; all 8 half-waves round-robin over it (perfect balance, independent
// iterations), accumulating into an fp32 LDS tile with ds_add_f32.
// agg layout is PERMUTED: logical dword d lives at phys (d&3)*32 + (d>>2),
// so lane l32's four component-adds all hit bank l32 (2 lanes/bank over
// wave64 = conflict-free).
__global__ __launch_bounds__(256) void mlp_kernel(
    const float* __restrict__ x, const float* __restrict__ edge_attr,
    const int* __restrict__ starts, const int* __restrict__ edge_ids,
    const int* __restrict__ recvs,
    const unsigned short* __restrict__ pW1, const unsigned short* __restrict__ pW2,
    const float* __restrict__ b1, const float* __restrict__ b2,
    float* __restrict__ out, int n_nodes)
{
    __shared__ unsigned short in_s[NPB][2 * D + 8];  // +8 bf16 pad -> 2-way LDS aliasing (free)
    __shared__ float agg[NPB][D];                    // fp32 accumulators (permuted layout)
    // h_s overlays agg: agg is fully consumed (convert phase + barrier) before
    // the first h_s write in the layer-1 epilogue.
    unsigned short (*h_s)[D + 8] = (unsigned short (*)[D + 8])(&agg[0][0]);

    const int t = threadIdx.x;
    const int node0 = blockIdx.x * NPB;

    // zero agg
    for (int i = t; i < NPB * D; i += 256) (&agg[0][0])[i] = 0.f;

    // stage x rows as bf16
    for (int i = t; i < NPB * 32; i += 256) {
        int m = i >> 5, c4 = i & 31;
        int node = node0 + m;
        float4 v = make_float4(0.f, 0.f, 0.f, 0.f);
        if (node < n_nodes) v = *(const float4*)(x + (size_t)node * D + c4 * 4);
        ushort4 b;
        b.x = f2bf(v.x); b.y = f2bf(v.y); b.z = f2bf(v.z); b.w = f2bf(v.w);
        *(ushort4*)(&in_s[m][c4 * 4]) = b;
    }
    __syncthreads();   // agg zeroed before atomics

    // edge-parallel gather over the block's contiguous sorted-edge range
    {
        int nhi = node0 + NPB; if (nhi > n_nodes) nhi = n_nodes;
        const int e0 = starts[node0];
        const int e1 = starts[nhi];
        const int g = t >> 5, l32 = t & 31;
#pragma unroll 2
        for (int p = e0 + g; p < e1; p += 8) {
            int e = edge_ids[p];
            int r = recvs[p] - node0;          // 0..NPB-1 by CSR construction
            float4 v = *(const float4*)(edge_attr + (size_t)e * D + l32 * 4);
            atomicAdd(&agg[r][l32],      v.x);  // logical d=4*l32+0 -> phys 0*32+l32
            atomicAdd(&agg[r][32 + l32], v.y);  // logical d=4*l32+1 -> phys 1*32+l32
            atomicAdd(&agg[r][64 + l32], v.z);
            atomicAdd(&agg[r][96 + l32], v.w);
        }
    }
    __syncthreads();

    // convert permuted fp32 agg -> bf16 in_s[:, D..2D)
    for (int i = t; i < NPB * 32; i += 256) {
        int m = i >> 5, q = i & 31;
        ushort4 b;
        b.x = f2bf(agg[m][q]);          // logical d = 4q+0
        b.y = f2bf(agg[m][32 + q]);     // logical d = 4q+1
        b.z = f2bf(agg[m][64 + q]);
        b.w = f2bf(agg[m][96 + q]);
        *(ushort4*)(&in_s[m][D + q * 4]) = b;
    }
    __syncthreads();   // agg fully consumed; h_s overlay now safe

    const int w = t >> 6, l = t & 63;
    const int col = l & 15, quad = l >> 4;
    const int c0 = w * 2, c1 = c0 + 1;

    // ---- layer 1: [32 x 256] @ [256 x 128], wave w owns col-tiles c0,c1 ----
    f32x4 a00, a01, a10, a11;
    {
        float bA = b1[c0 * 16 + col], bB = b1[c1 * 16 + col];
        a00 = (f32x4){bA, bA, bA, bA}; a01 = (f32x4){bB, bB, bB, bB};
        a10 = a00; a11 = a01;
    }
#pragma unroll
    for (int s = 0; s < 8; ++s) {
        short8 fa0 = *(const short8*)(&in_s[col][s * 32 + quad * 8]);
        short8 fa1 = *(const short8*)(&in_s[16 + col][s * 32 + quad * 8]);
        short8 fb0 = *(const short8*)(pW1 + (((c0 * 8 + s) * 64 + l) * 8));
        short8 fb1 = *(const short8*)(pW1 + (((c1 * 8 + s) * 64 + l) * 8));
        a00 = __builtin_amdgcn_mfma_f32_16x16x32_bf16(fa0, fb0, a00, 0, 0, 0);
        a01 = __builtin_amdgcn_mfma_f32_16x16x32_bf16(fa0, fb1, a01, 0, 0, 0);
        a10 = __builtin_amdgcn_mfma_f32_16x16x32_bf16(fa1, fb0, a10, 0, 0, 0);
        a11 = __builtin_amdgcn_mfma_f32_16x16x32_bf16(fa1, fb1, a11, 0, 0, 0);
    }
#pragma unroll
    for (int r = 0; r < 4; ++r) {
        int row = quad * 4 + r;   // C/D: col = l&15, row = quad*4 + reg
        h_s[row][c0 * 16 + col]      = f2bf(fmaxf(a00[r], 0.f));
        h_s[row][c1 * 16 + col]      = f2bf(fmaxf(a01[r], 0.f));
        h_s[16 + row][c0 * 16 + col] = f2bf(fmaxf(a10[r], 0.f));
        h_s[16 + row][c1 * 16 + col] = f2bf(fmaxf(a11[r], 0.f));
    }
    __syncthreads();

    // ---- layer 2: [32 x 128] @ [128 x 128] ----
    f32x4 o00, o01, o10, o11;
    {
        float bA = b2[c0 * 16 + col], bB = b2[c1 * 16 + col];
        o00 = (f32x4){bA, bA, bA, bA}; o01 = (f32x4){bB, bB, bB, bB};
        o10 = o00; o11 = o01;
    }
#pragma unroll
    for (int s = 0; s < 4; ++s) {
        short8 fa0 = *(const short8*)(&h_s[col][s * 32 + quad * 8]);
        short8 fa1 = *(const short8*)(&h_s[16 + col][s * 32 + quad * 8]);
        short8 fb0 = *(const short8*)(pW2 + (((c0 * 4 + s) * 64 + l) * 8));
        short8 fb1 = *(const short8*)(pW2 + (((c1 * 4 + s) * 64 + l) * 8));
        o00 = __builtin_amdgcn_mfma_f32_16x16x32_bf16(fa0, fb0, o00, 0, 0, 0);
        o01 = __builtin_amdgcn_mfma_f32_16x16x32_bf16(fa0, fb1, o01, 0, 0, 0);
        o10 = __builtin_amdgcn_mfma_f32_16x16x32_bf16(fa1, fb0, o10, 0, 0, 0);
        o11 = __builtin_amdgcn_mfma_f32_16x16x32_bf16(fa1, fb1, o11, 0, 0, 0);
    }
#pragma unroll
    for (int r = 0; r < 4; ++r) {
        int row = quad * 4 + r;
        int na = node0 + row, nb = node0 + 16 + row;
        if (na < n_nodes) {
            out[(size_t)na * D + c0 * 16 + col] = o00[r];
            out[(size_t)na * D + c1 * 16 + col] = o01[r];
        }
        if (nb < n_nodes) {
            out[(size_t)nb * D + c0 * 16 + col] = o10[r];
            out[(size_t)nb * D + c1 * 16 + col] = o11[r];
        }
    }
}

extern "C" void kernel_launch(void* const* d_in, const int* in_sizes, int n_in,
                              void* d_out, int out_size, void* d_ws, size_t ws_size,
                              hipStream_t stream) {
    const float* x         = (const float*)d_in[0];
    const float* edge_attr = (const float*)d_in[1];
    const int*   edge_index= (const int*)d_in[2];
    const float* W1        = (const float*)d_in[3];
    const float* b1        = (const float*)d_in[4];
    const float* W2        = (const float*)d_in[5];
    const float* b2        = (const float*)d_in[6];
    float* out = (float*)d_out;

    const int n_nodes = in_sizes[0] / D;       // 200000
    const int n_edges = in_sizes[1] / D;       // 800000
    const int* recv = edge_index + n_edges;    // row 1 of [2, E]

    char* wsb = (char*)d_ws;
    int* counts   = (int*)(wsb + 0);                         // 800 KB
    int* cursor   = (int*)(wsb + (1u << 20));                // 800 KB
    int* starts   = (int*)(wsb + (2u << 20));                // 800 KB + 4
    int* blocksum = (int*)(wsb + (3u << 20));                // ~4 KB
    int* edge_ids = (int*)(wsb + (4u << 20));                // 3.2 MB
    int* recvs_s  = (int*)(wsb + (8u << 20));                // 3.2 MB
    unsigned short* pW1 = (unsigned short*)(wsb + (12u << 20));               // 64 KB
    unsigned short* pW2 = (unsigned short*)(wsb + (12u << 20) + (1u << 17));  // 32 KB

    setup_kernel<<<400, 256, 0, stream>>>(W1, W2, pW1, pW2, counts, n_nodes);

    const int eb = (n_edges + 255) / 256;
    hist_kernel<<<eb, 256, 0, stream>>>(recv, counts, n_edges);

    const int nb = (n_nodes + 255) / 256;      // 782
    reduce_kernel<<<nb, 256, 0, stream>>>(counts, blocksum, n_nodes);
    scan_kernel<<<nb, 256, 0, stream>>>(counts, blocksum, starts, cursor, n_nodes);
    reorder_kernel<<<eb, 256, 0, stream>>>(recv, cursor, edge_ids, recvs_s, n_edges);

    mlp_kernel<<<(n_nodes + NPB - 1) / NPB, 256, 0, stream>>>(
        x, edge_attr, starts, edge_ids, recvs_s, pW1, pW2, b1, b2, out, n_nodes);
}

// Round 2
// 772.165 us; speedup vs baseline: 1.4374x; 1.4374x over previous
//
#include <hip/hip_runtime.h>

#define D 128
#define NPB 32  // nodes per MLP block

typedef __attribute__((ext_vector_type(8))) short short8;
typedef __attribute__((ext_vector_type(4))) float f32x4;

__device__ inline unsigned short f2bf(float f) {
    unsigned int u = __float_as_uint(f);
    u += 0x7fffu + ((u >> 16) & 1u);   // round-to-nearest-even
    return (unsigned short)(u >> 16);
}

// ---- pack W1 [2D,D] and W2 [D,D] into MFMA B-fragment order (bf16) + zero counts ----
// B-frag for (col-tile c, k-step s): lane l holds B[k][n], n = c*16 + (l&15),
// k = s*32 + (l>>4)*8 + j, j=0..7 contiguous -> one 16B load per fragment.
__global__ __launch_bounds__(256) void setup_kernel(
    const float* __restrict__ W1, const float* __restrict__ W2,
    unsigned short* __restrict__ pW1, unsigned short* __restrict__ pW2,
    int* __restrict__ counts, int n_nodes)
{
    int idx = blockIdx.x * 256 + threadIdx.x;
    if (idx < 32768) {            // 8 c-tiles * 8 s-steps * 64 lanes * 8
        int j = idx & 7, lane = (idx >> 3) & 63, s = (idx >> 9) & 7, c = idx >> 12;
        int k = s * 32 + ((lane >> 4) << 3) + j;
        int n = (c << 4) + (lane & 15);
        pW1[idx] = f2bf(W1[k * D + n]);
    } else if (idx < 49152) {     // 8 c-tiles * 4 s-steps * 64 lanes * 8
        int i2 = idx - 32768;
        int j = i2 & 7, lane = (i2 >> 3) & 63, s = (i2 >> 9) & 3, c = i2 >> 11;
        int k = s * 32 + ((lane >> 4) << 3) + j;
        int n = (c << 4) + (lane & 15);
        pW2[i2] = f2bf(W2[k * D + n]);
    }
    // zero histogram counts (replaces a separate hipMemsetAsync dispatch)
    for (int i = idx; i < n_nodes; i += gridDim.x * 256) counts[i] = 0;
}

// ---- CSR build: histogram -> (reduce, fused scan) -> reorder ----
__global__ __launch_bounds__(256) void hist_kernel(
    const int* __restrict__ recv, int* __restrict__ counts, int n_edges)
{
    int e = blockIdx.x * 256 + threadIdx.x;
    if (e < n_edges) atomicAdd(&counts[recv[e]], 1);
}

__global__ __launch_bounds__(256) void reduce_kernel(
    const int* __restrict__ counts, int* __restrict__ blocksum, int n)
{
    __shared__ int s[256];
    int t = threadIdx.x, i = blockIdx.x * 256 + t;
    s[t] = (i < n) ? counts[i] : 0;
    __syncthreads();
    for (int off = 128; off > 0; off >>= 1) {
        if (t < off) s[t] += s[t + off];
        __syncthreads();
    }
    if (t == 0) blocksum[blockIdx.x] = s[0];
}

// fused: block b computes its own exclusive offset by summing blocksum[0..b)
// (L2-resident -> trivial), then does the intra-block scan.
__global__ __launch_bounds__(256) void scan_kernel(
    const int* __restrict__ counts, const int* __restrict__ blocksum,
    int* __restrict__ starts, int* __restrict__ cursor, int n)
{
    __shared__ int s[256];
    int t = threadIdx.x, b = blockIdx.x, i = b * 256 + t;

    int acc = 0;
    for (int j = t; j < b; j += 256) acc += blocksum[j];
    s[t] = acc;
    __syncthreads();
    for (int off = 128; off > 0; off >>= 1) {
        if (t < off) s[t] += s[t + off];
        __syncthreads();
    }
    int blockoff = s[0];
    __syncthreads();   // everyone has read s[0] before s[] is reused

    int v = (i < n) ? counts[i] : 0;
    s[t] = v;
    __syncthreads();
    for (int off = 1; off < 256; off <<= 1) {
        int add = (t >= off) ? s[t - off] : 0;
        __syncthreads();
        s[t] += add;
        __syncthreads();
    }
    int excl = s[t] - v + blockoff;
    if (i < n) {
        starts[i] = excl;
        cursor[i] = excl;
        if (i == n - 1) starts[n] = excl + v;
    }
}

__global__ __launch_bounds__(256) void reorder_kernel(
    const int* __restrict__ recv, int* __restrict__ cursor,
    int* __restrict__ edge_ids, int n_edges)
{
    int e = blockIdx.x * 256 + threadIdx.x;
    if (e < n_edges) {
        int r = recv[e];
        int pos = atomicAdd(&cursor[r], 1);
        edge_ids[pos] = e;
    }
}

// ---- gather: half-wave (32 lanes) per node, register fp32 accumulate ----
// No LDS, no barriers -> 32 waves/CU of TLP to hide the edge_ids -> edge_attr
// dependent-load chain. Writes agg as bf16 [N, D] (51 MB) to workspace.
__global__ __launch_bounds__(256) void gather_kernel(
    const float* __restrict__ edge_attr,
    const int* __restrict__ starts, const int* __restrict__ edge_ids,
    unsigned short* __restrict__ aggb, int n_nodes)
{
    const int g = threadIdx.x >> 5, l32 = threadIdx.x & 31;
    const int stride = gridDim.x * 8;
    for (int node = blockIdx.x * 8 + g; node < n_nodes; node += stride) {
        int p = starts[node], pe = starts[node + 1];
        float4 acc = make_float4(0.f, 0.f, 0.f, 0.f);
        // unroll-4: four independent rows in flight per batch
        for (; p + 3 < pe; p += 4) {
            int e0 = edge_ids[p], e1 = edge_ids[p + 1];
            int e2 = edge_ids[p + 2], e3 = edge_ids[p + 3];
            float4 v0 = *(const float4*)(edge_attr + (size_t)e0 * D + l32 * 4);
            float4 v1 = *(const float4*)(edge_attr + (size_t)e1 * D + l32 * 4);
            float4 v2 = *(const float4*)(edge_attr + (size_t)e2 * D + l32 * 4);
            float4 v3 = *(const float4*)(edge_attr + (size_t)e3 * D + l32 * 4);
            acc.x += (v0.x + v1.x) + (v2.x + v3.x);
            acc.y += (v0.y + v1.y) + (v2.y + v3.y);
            acc.z += (v0.z + v1.z) + (v2.z + v3.z);
            acc.w += (v0.w + v1.w) + (v2.w + v3.w);
        }
        for (; p < pe; ++p) {
            int e0 = edge_ids[p];
            float4 v0 = *(const float4*)(edge_attr + (size_t)e0 * D + l32 * 4);
            acc.x += v0.x; acc.y += v0.y; acc.z += v0.z; acc.w += v0.w;
        }
        ushort4 b;
        b.x = f2bf(acc.x); b.y = f2bf(acc.y); b.z = f2bf(acc.z); b.w = f2bf(acc.w);
        *(ushort4*)(aggb + (size_t)node * D + l32 * 4) = b;
    }
}

// ---- MLP: pure streaming (x fp32 + agg bf16 in, out fp32), bf16 MFMA ----
__global__ __launch_bounds__(256) void mlp_kernel(
    const float* __restrict__ x, const unsigned short* __restrict__ aggb,
    const unsigned short* __restrict__ pW1, const unsigned short* __restrict__ pW2,
    const float* __restrict__ b1, const float* __restrict__ b2,
    float* __restrict__ out, int n_nodes)
{
    __shared__ unsigned short in_s[NPB][2 * D + 8];  // +8 bf16 pad -> 2-way LDS aliasing (free)
    __shared__ unsigned short h_s[NPB][D + 8];

    const int t = threadIdx.x;
    const int node0 = blockIdx.x * NPB;

    // stage x rows as bf16
    for (int i = t; i < NPB * 32; i += 256) {
        int m = i >> 5, c4 = i & 31;
        int node = node0 + m;
        float4 v = make_float4(0.f, 0.f, 0.f, 0.f);
        if (node < n_nodes) v = *(const float4*)(x + (size_t)node * D + c4 * 4);
        ushort4 b;
        b.x = f2bf(v.x); b.y = f2bf(v.y); b.z = f2bf(v.z); b.w = f2bf(v.w);
        *(ushort4*)(&in_s[m][c4 * 4]) = b;
    }
    // stage agg rows (already bf16: straight ushort4 copy)
    for (int i = t; i < NPB * 32; i += 256) {
        int m = i >> 5, c4 = i & 31;
        int node = node0 + m;
        ushort4 b = make_ushort4(0, 0, 0, 0);
        if (node < n_nodes) b = *(const ushort4*)(aggb + (size_t)node * D + c4 * 4);
        *(ushort4*)(&in_s[m][D + c4 * 4]) = b;
    }
    __syncthreads();

    const int w = t >> 6, l = t & 63;
    const int col = l & 15, quad = l >> 4;
    const int c0 = w * 2, c1 = c0 + 1;

    // ---- layer 1: [32 x 256] @ [256 x 128], wave w owns col-tiles c0,c1 ----
    f32x4 a00, a01, a10, a11;
    {
        float bA = b1[c0 * 16 + col], bB = b1[c1 * 16 + col];
        a00 = (f32x4){bA, bA, bA, bA}; a01 = (f32x4){bB, bB, bB, bB};
        a10 = a00; a11 = a01;
    }
#pragma unroll
    for (int s = 0; s < 8; ++s) {
        short8 fa0 = *(const short8*)(&in_s[col][s * 32 + quad * 8]);
        short8 fa1 = *(const short8*)(&in_s[16 + col][s * 32 + quad * 8]);
        short8 fb0 = *(const short8*)(pW1 + (((c0 * 8 + s) * 64 + l) * 8));
        short8 fb1 = *(const short8*)(pW1 + (((c1 * 8 + s) * 64 + l) * 8));
        a00 = __builtin_amdgcn_mfma_f32_16x16x32_bf16(fa0, fb0, a00, 0, 0, 0);
        a01 = __builtin_amdgcn_mfma_f32_16x16x32_bf16(fa0, fb1, a01, 0, 0, 0);
        a10 = __builtin_amdgcn_mfma_f32_16x16x32_bf16(fa1, fb0, a10, 0, 0, 0);
        a11 = __builtin_amdgcn_mfma_f32_16x16x32_bf16(fa1, fb1, a11, 0, 0, 0);
    }
#pragma unroll
    for (int r = 0; r < 4; ++r) {
        int row = quad * 4 + r;   // C/D: col = l&15, row = quad*4 + reg
        h_s[row][c0 * 16 + col]      = f2bf(fmaxf(a00[r], 0.f));
        h_s[row][c1 * 16 + col]      = f2bf(fmaxf(a01[r], 0.f));
        h_s[16 + row][c0 * 16 + col] = f2bf(fmaxf(a10[r], 0.f));
        h_s[16 + row][c1 * 16 + col] = f2bf(fmaxf(a11[r], 0.f));
    }
    __syncthreads();

    // ---- layer 2: [32 x 128] @ [128 x 128] ----
    f32x4 o00, o01, o10, o11;
    {
        float bA = b2[c0 * 16 + col], bB = b2[c1 * 16 + col];
        o00 = (f32x4){bA, bA, bA, bA}; o01 = (f32x4){bB, bB, bB, bB};
        o10 = o00; o11 = o01;
    }
#pragma unroll
    for (int s = 0; s < 4; ++s) {
        short8 fa0 = *(const short8*)(&h_s[col][s * 32 + quad * 8]);
        short8 fa1 = *(const short8*)(&h_s[16 + col][s * 32 + quad * 8]);
        short8 fb0 = *(const short8*)(pW2 + (((c0 * 4 + s) * 64 + l) * 8));
        short8 fb1 = *(const short8*)(pW2 + (((c1 * 4 + s) * 64 + l) * 8));
        o00 = __builtin_amdgcn_mfma_f32_16x16x32_bf16(fa0, fb0, o00, 0, 0, 0);
        o01 = __builtin_amdgcn_mfma_f32_16x16x32_bf16(fa0, fb1, o01, 0, 0, 0);
        o10 = __builtin_amdgcn_mfma_f32_16x16x32_bf16(fa1, fb0, o10, 0, 0, 0);
        o11 = __builtin_amdgcn_mfma_f32_16x16x32_bf16(fa1, fb1, o11, 0, 0, 0);
    }
#pragma unroll
    for (int r = 0; r < 4; ++r) {
        int row = quad * 4 + r;
        int na = node0 + row, nb = node0 + 16 + row;
        if (na < n_nodes) {
            out[(size_t)na * D + c0 * 16 + col] = o00[r];
            out[(size_t)na * D + c1 * 16 + col] = o01[r];
        }
        if (nb < n_nodes) {
            out[(size_t)nb * D + c0 * 16 + col] = o10[r];
            out[(size_t)nb * D + c1 * 16 + col] = o11[r];
        }
    }
}

extern "C" void kernel_launch(void* const* d_in, const int* in_sizes, int n_in,
                              void* d_out, int out_size, void* d_ws, size_t ws_size,
                              hipStream_t stream) {
    const float* x         = (const float*)d_in[0];
    const float* edge_attr = (const float*)d_in[1];
    const int*   edge_index= (const int*)d_in[2];
    const float* W1        = (const float*)d_in[3];
    const float* b1        = (const float*)d_in[4];
    const float* W2        = (const float*)d_in[5];
    const float* b2        = (const float*)d_in[6];
    float* out = (float*)d_out;

    const int n_nodes = in_sizes[0] / D;       // 200000
    const int n_edges = in_sizes[1] / D;       // 800000
    const int* recv = edge_index + n_edges;    // row 1 of [2, E]

    char* wsb = (char*)d_ws;
    int* counts   = (int*)(wsb + 0);                         // 800 KB
    int* cursor   = (int*)(wsb + (1u << 20));                // 800 KB
    int* starts   = (int*)(wsb + (2u << 20));                // 800 KB + 4
    int* blocksum = (int*)(wsb + (3u << 20));                // ~4 KB
    int* edge_ids = (int*)(wsb + (4u << 20));                // 3.2 MB
    unsigned short* pW1 = (unsigned short*)(wsb + (8u << 20));               // 64 KB
    unsigned short* pW2 = (unsigned short*)(wsb + (8u << 20) + (1u << 17));  // 32 KB
    unsigned short* aggb = (unsigned short*)(wsb + (16u << 20));             // 51.2 MB

    setup_kernel<<<400, 256, 0, stream>>>(W1, W2, pW1, pW2, counts, n_nodes);

    const int eb = (n_edges + 255) / 256;
    hist_kernel<<<eb, 256, 0, stream>>>(recv, counts, n_edges);

    const int nb = (n_nodes + 255) / 256;      // 782
    reduce_kernel<<<nb, 256, 0, stream>>>(counts, blocksum, n_nodes);
    scan_kernel<<<nb, 256, 0, stream>>>(counts, blocksum, starts, cursor, n_nodes);
    reorder_kernel<<<eb, 256, 0, stream>>>(recv, cursor, edge_ids, n_edges);

    gather_kernel<<<2048, 256, 0, stream>>>(edge_attr, starts, edge_ids, aggb, n_nodes);

    mlp_kernel<<<(n_nodes + NPB - 1) / NPB, 256, 0, stream>>>(
        x, aggb, pW1, pW2, b1, b2, out, n_nodes);
}